// Round 7
// baseline (1306.817 us; speedup 1.0000x reference)
//
#include <hip/hip_runtime.h>
#include <hip/hip_fp16.h>

#define N_FM 100000
#define N_TP 4096
#define N_SM 100000
#define HID 128
#define E_QOQ 1000000
#define E_BP 1000000
#define E_CP 500000
#define E_CD 500000
#define E_RB 1000000
#define TR 32  // rows per tile

typedef _Float16 h2 __attribute__((ext_vector_type(2)));

#if defined(__has_builtin)
#if __has_builtin(__builtin_amdgcn_fdot2)
#define HAVE_FDOT2 1
#endif
#endif

union U32H2 { unsigned u; h2 h; };

__device__ __forceinline__ unsigned pk2(float a, float b) {
    U32H2 x; x.h = h2{(_Float16)a, (_Float16)b}; return x.u;
}
// acc += dot(a_pair, b_pair), fp32 accumulate
__device__ __forceinline__ float dot2(float acc, unsigned a, unsigned b) {
    U32H2 x, y; x.u = a; y.u = b;
#ifdef HAVE_FDOT2
    return __builtin_amdgcn_fdot2(x.h, y.h, acc, false);
#else
    return acc + (float)x.h[0] * (float)y.h[0] + (float)x.h[1] * (float)y.h[1];
#endif
}

// ---------------------------------------------------------------- packing kernels
__global__ void pe_pack_kernel(const float* __restrict__ pe_table, const float* __restrict__ pvol,
                               unsigned* __restrict__ pe_f) {
    int i = blockIdx.x * blockDim.x + threadIdx.x;  // pair index
    if (i < N_TP * 16) {
        float2 t = ((const float2*)pe_table)[i];
        float v = pvol[i >> 4];
        pe_f[i] = pk2(t.x * v, t.y * v);
    }
}

__global__ void pack_x_kernel(const float* __restrict__ x, unsigned* __restrict__ xp, int npairs) {
    int i = blockIdx.x * blockDim.x + threadIdx.x;
    if (i < npairs) {
        float2 t = ((const float2*)x)[i];
        xp[i] = pk2(t.x, t.y);
    }
}

__global__ void wr_comb_kernel(const float* __restrict__ a, const float* __restrict__ b,
                               const float* __restrict__ c, float* __restrict__ o) {
    int i = blockIdx.x * blockDim.x + threadIdx.x;
    if (i < 64 * HID) o[i] = a[i] + b[i] + c[i];
}

// W[K][128] fp32 -> f16 pairs [K/2][128]
__global__ void pack_w_kernel(const float* __restrict__ W, unsigned* __restrict__ dst, int K) {
    int i = blockIdx.x * blockDim.x + threadIdx.x;
    int n = (K / 2) * HID;
    if (i < n) {
        int r = i >> 7, c = i & 127;
        dst[i] = pk2(W[(2 * r) * HID + c], W[(2 * r + 1) * HID + c]);
    }
}

// ---------------------------------------------------------------- counting sort: hist -> scan -> place
__global__ void hist_kernel(const int* __restrict__ dst, int nE, int* __restrict__ cnt) {
    int stride = gridDim.x * blockDim.x;
    for (int e = blockIdx.x * blockDim.x + threadIdx.x; e < nE; e += stride)
        atomicAdd(&cnt[dst[e]], 1);
}

// one block per relation; cnt may alias woffs (read-before-write per element)
__global__ void __launch_bounds__(1024) scan_kernel(
    int* c0, int* o0, int n0, int* c1, int* o1, int n1, int* c2, int* o2, int n2,
    int* c3, int* o3, int n3, int* c4, int* o4, int n4) {
    int* cnt; int* offs; int n;
    switch (blockIdx.x) {
        case 0: cnt = c0; offs = o0; n = n0; break;
        case 1: cnt = c1; offs = o1; n = n1; break;
        case 2: cnt = c2; offs = o2; n = n2; break;
        case 3: cnt = c3; offs = o3; n = n3; break;
        default: cnt = c4; offs = o4; n = n4; break;
    }
    __shared__ int ssum[1024];
    const int t = threadIdx.x;
    const int C = (n + 1023) >> 10;
    const int b = t * C, e = min(b + C, n);
    int local = 0;
    for (int i = b; i < e; i++) local += cnt[i];
    ssum[t] = local;
    __syncthreads();
    for (int off = 1; off < 1024; off <<= 1) {
        int v = (t >= off) ? ssum[t - off] : 0;
        __syncthreads();
        ssum[t] += v;
        __syncthreads();
    }
    int total = ssum[1023];
    int pre = (t == 0) ? 0 : ssum[t - 1];
    for (int i = b; i < e; i++) {
        int v = cnt[i];
        offs[i] = pre;
        cnt[i] = pre;  // cnt doubles as the working-offset array for place_kernel
        pre += v;
    }
    if (t == 0) offs[n] = total;
}

__global__ void place_kernel(const int* __restrict__ src, const int* __restrict__ dst, int nE,
                             int* __restrict__ woffs, int* __restrict__ sorted_src) {
    int stride = gridDim.x * blockDim.x;
    for (int e = blockIdx.x * blockDim.x + threadIdx.x; e < nE; e += stride) {
        int p = atomicAdd(&woffs[dst[e]], 1);
        sorted_src[p] = src[e];
    }
}

// ---------------------------------------------------------------- gather-reduce: CSR -> packed f16 means
// P = pairs per feature row (32 for 64 feats, 16 for 32 feats); P lanes cooperate per dst.
template <int LOGP>
__global__ void gather_mean(const int* __restrict__ offs, int ndst,
                            const int* __restrict__ ssrc, const unsigned* __restrict__ feat,
                            unsigned* __restrict__ mean) {
    const int P = 1 << LOGP;
    int gid = blockIdx.x * blockDim.x + threadIdx.x;
    int g = gid >> LOGP;
    if (g >= ndst) return;
    int lane = gid & (P - 1);
    int beg = offs[g], end = offs[g + 1];
    float alo = 0.0f, ahi = 0.0f;
    int i = beg;
    for (; i + 4 <= end; i += 4) {
        int s0 = ssrc[i], s1 = ssrc[i + 1], s2 = ssrc[i + 2], s3 = ssrc[i + 3];
        unsigned v0 = feat[(size_t)s0 * P + lane];
        unsigned v1 = feat[(size_t)s1 * P + lane];
        unsigned v2 = feat[(size_t)s2 * P + lane];
        unsigned v3 = feat[(size_t)s3 * P + lane];
        U32H2 u;
        u.u = v0; alo += (float)u.h[0]; ahi += (float)u.h[1];
        u.u = v1; alo += (float)u.h[0]; ahi += (float)u.h[1];
        u.u = v2; alo += (float)u.h[0]; ahi += (float)u.h[1];
        u.u = v3; alo += (float)u.h[0]; ahi += (float)u.h[1];
    }
    for (; i < end; i++) {
        unsigned v = feat[(size_t)ssrc[i] * P + lane];
        U32H2 u; u.u = v;
        alo += (float)u.h[0]; ahi += (float)u.h[1];
    }
    float ic = (end > beg) ? 1.0f / (float)(end - beg) : 0.0f;
    mean[(size_t)g * P + lane] = pk2(alo * ic, ahi * ic);
}

// ---------------------------------------------------------------- LN + relu + colsum epilogue
__device__ __forceinline__ void ln_relu_colsum(float accv[TR], float gc, float bc,
                                               float (*s_w)[TR], float (*s_q)[TR],
                                               float& colacc, int c) {
    int wid = c >> 6;
#pragma unroll
    for (int r = 0; r < TR; r++) {
        float s = accv[r], q = accv[r] * accv[r];
#pragma unroll
        for (int off = 1; off < 64; off <<= 1) {
            s += __shfl_xor(s, off);
            q += __shfl_xor(q, off);
        }
        if ((c & 63) == 0) { s_w[wid][r] = s; s_q[wid][r] = q; }
    }
    __syncthreads();
#pragma unroll
    for (int r = 0; r < TR; r++) {
        float tot = s_w[0][r] + s_w[1][r], totq = s_q[0][r] + s_q[1][r];
        float mu = tot * (1.0f / 128.0f);
        float var = fmaxf(totq * (1.0f / 128.0f) - mu * mu, 0.0f);
        float y = (accv[r] - mu) * rsqrtf(var + 1e-5f) * gc + bc;
        colacc += fmaxf(y, 0.0f);
    }
    __syncthreads();
}

// ---------------------------------------------------------------- fm rows (f16 packed means, fdot2)
// s_in pair layout: [0..31]=qoq mean | [32..47]=cp mean | [48..63]=rb mean | [64..95]=x_fm
__global__ void __launch_bounds__(128, 3)
fm_rows_f16(const unsigned* __restrict__ mean_qoq, const unsigned* __restrict__ mean_cp,
            const unsigned* __restrict__ mean_rb, const unsigned* __restrict__ x_fm_f,
            const unsigned* __restrict__ wf,
            const float* __restrict__ bl_q, const float* __restrict__ bl_c,
            const float* __restrict__ bl_r,
            const float* __restrict__ ln_g, const float* __restrict__ ln_b,
            float* __restrict__ colsum) {
    const int c = threadIdx.x;  // 0..127
    __shared__ __align__(16) unsigned s_in[TR][96];
    __shared__ float s_w[2][TR], s_q[2][TR];
    const float bias = bl_q[c] + bl_c[c] + bl_r[c];
    const float gc = ln_g[c], bc = ln_b[c];
    float colacc = 0.0f;
    const int ntiles = N_FM / TR;
    for (int tile = blockIdx.x; tile < ntiles; tile += gridDim.x) {
        const size_t row0 = (size_t)tile * TR;
        for (int i = c; i < TR * 8; i += 128) {
            int r = i >> 3;
            *(uint4*)&s_in[r][(i & 7) * 4] = ((const uint4*)mean_qoq)[row0 * 8 + i];
        }
        for (int i = c; i < TR * 4; i += 128) {
            int r = i >> 2;
            *(uint4*)&s_in[r][32 + (i & 3) * 4] = ((const uint4*)mean_cp)[row0 * 4 + i];
        }
        for (int i = c; i < TR * 4; i += 128) {
            int r = i >> 2;
            *(uint4*)&s_in[r][48 + (i & 3) * 4] = ((const uint4*)mean_rb)[row0 * 4 + i];
        }
        for (int i = c; i < TR * 8; i += 128) {
            int r = i >> 3;
            *(uint4*)&s_in[r][64 + (i & 7) * 4] = ((const uint4*)x_fm_f)[row0 * 8 + i];
        }
        __syncthreads();
        float accv[TR];
#pragma unroll
        for (int r = 0; r < TR; r++) accv[r] = 0.0f;
        for (int p = 0; p < 96; p += 4) {
            unsigned w0 = wf[(p + 0) * HID + c], w1 = wf[(p + 1) * HID + c];
            unsigned w2 = wf[(p + 2) * HID + c], w3 = wf[(p + 3) * HID + c];
#pragma unroll
            for (int r = 0; r < TR; r++) {
                uint4 v = *(const uint4*)&s_in[r][p];
                accv[r] = dot2(dot2(dot2(dot2(accv[r], v.x, w0), v.y, w1), v.z, w2), v.w, w3);
            }
        }
#pragma unroll
        for (int r = 0; r < TR; r++) accv[r] = (accv[r] + bias) * (1.0f / 3.0f);
        ln_relu_colsum(accv, gc, bc, s_w, s_q, colacc, c);
    }
    unsafeAtomicAdd(&colsum[c], colacc);
}

// ---------------------------------------------------------------- generic rows (f16 packed means)
template <int PA, int PB>
__global__ void __launch_bounds__(128, 3)
rows_f16(int ntiles, const unsigned* __restrict__ meanA, const unsigned* __restrict__ xB,
         const unsigned* __restrict__ wf, const float* __restrict__ bl,
         const float* __restrict__ ln_g, const float* __restrict__ ln_b,
         float* __restrict__ colsum) {
    const int c = threadIdx.x;  // 0..127
    __shared__ __align__(16) unsigned s_in[TR][PA + PB];
    __shared__ float s_w[2][TR], s_q[2][TR];
    const float bias = bl[c];
    const float gc = ln_g[c], bc = ln_b[c];
    float colacc = 0.0f;
    const int A4 = PA / 4, B4 = PB / 4;
    for (int tile = blockIdx.x; tile < ntiles; tile += gridDim.x) {
        const size_t row0 = (size_t)tile * TR;
        for (int i = c; i < TR * A4; i += 128) {
            int r = i / A4, q = i % A4;
            *(uint4*)&s_in[r][q * 4] = ((const uint4*)meanA)[row0 * A4 + i];
        }
        for (int i = c; i < TR * B4; i += 128) {
            int r = i / B4, q = i % B4;
            *(uint4*)&s_in[r][PA + q * 4] = ((const uint4*)xB)[row0 * B4 + i];
        }
        __syncthreads();
        float accv[TR];
#pragma unroll
        for (int r = 0; r < TR; r++) accv[r] = 0.0f;
        for (int p = 0; p < PA + PB; p += 4) {
            unsigned w0 = wf[(p + 0) * HID + c], w1 = wf[(p + 1) * HID + c];
            unsigned w2 = wf[(p + 2) * HID + c], w3 = wf[(p + 3) * HID + c];
#pragma unroll
            for (int r = 0; r < TR; r++) {
                uint4 v = *(const uint4*)&s_in[r][p];
                accv[r] = dot2(dot2(dot2(dot2(accv[r], v.x, w0), v.y, w1), v.z, w2), v.w, w3);
            }
        }
#pragma unroll
        for (int r = 0; r < TR; r++) accv[r] += bias;
        ln_relu_colsum(accv, gc, bc, s_w, s_q, colacc, c);
    }
    unsafeAtomicAdd(&colsum[c], colacc);
}

// ---------------------------------------------------------------- head MLP -> scalar
__global__ void head_kernel(const float* __restrict__ colsum, const float* __restrict__ gf,
                            const float* __restrict__ W1, const float* __restrict__ b1,
                            const float* __restrict__ W2, const float* __restrict__ b2,
                            float* __restrict__ out) {
    __shared__ float h[448];
    __shared__ float h1[64];
    int t = threadIdx.x;  // 512 threads
    if (t < 128) h[t] = colsum[t] * (1.0f / N_FM);
    else if (t < 256) h[t] = colsum[t] * (1.0f / N_TP);
    else if (t < 384) h[t] = colsum[t] * (1.0f / N_SM);
    else if (t < 448) h[t] = gf[t - 384];
    __syncthreads();
    if (t < 64) {
        float a = b1[t];
        for (int k = 0; k < 448; k++) a += h[k] * W1[k * 64 + t];
        h1[t] = fmaxf(a, 0.0f);
    }
    __syncthreads();
    if (t < 64) {
        float p = h1[t] * W2[t];
#pragma unroll
        for (int off = 1; off < 64; off <<= 1) p += __shfl_xor(p, off);
        if (t == 0) out[0] = p + b2[0];
    }
}

extern "C" void kernel_launch(void* const* d_in, const int* in_sizes, int n_in,
                              void* d_out, int out_size, void* d_ws, size_t ws_size,
                              hipStream_t stream) {
    const float* x_fm = (const float*)d_in[0];
    const float* x_sm = (const float*)d_in[1];
    const float* period_vol = (const float*)d_in[2];
    const float* gf = (const float*)d_in[3];
    const float* pe_table = (const float*)d_in[4];
    const int* qoq_src = (const int*)d_in[5];
    const int* qoq_dst = (const int*)d_in[6];
    const int* bp_src = (const int*)d_in[7];
    const int* bp_dst = (const int*)d_in[8];
    const int* cp_src = (const int*)d_in[9];
    const int* cp_dst = (const int*)d_in[10];
    const int* cd_src = (const int*)d_in[11];
    const int* cd_dst = (const int*)d_in[12];
    const int* rb_src = (const int*)d_in[13];
    const int* rb_dst = (const int*)d_in[14];
    const float* qoq_Wl = (const float*)d_in[15];
    const float* qoq_bl = (const float*)d_in[16];
    const float* qoq_Wr = (const float*)d_in[17];
    const float* bp_Wl = (const float*)d_in[18];
    const float* bp_bl = (const float*)d_in[19];
    const float* bp_Wr = (const float*)d_in[20];
    const float* cp_Wl = (const float*)d_in[21];
    const float* cp_bl = (const float*)d_in[22];
    const float* cp_Wr = (const float*)d_in[23];
    const float* cd_Wl = (const float*)d_in[24];
    const float* cd_bl = (const float*)d_in[25];
    const float* cd_Wr = (const float*)d_in[26];
    const float* rb_Wl = (const float*)d_in[27];
    const float* rb_bl = (const float*)d_in[28];
    const float* rb_Wr = (const float*)d_in[29];
    const float* ln_fm_g = (const float*)d_in[30];
    const float* ln_fm_b = (const float*)d_in[31];
    const float* ln_tp_g = (const float*)d_in[32];
    const float* ln_tp_b = (const float*)d_in[33];
    const float* ln_sm_g = (const float*)d_in[34];
    const float* ln_sm_b = (const float*)d_in[35];
    const float* head_W1 = (const float*)d_in[36];
    const float* head_b1 = (const float*)d_in[37];
    const float* head_W2 = (const float*)d_in[38];
    const float* head_b2 = (const float*)d_in[39];

    // workspace layout (4-byte words). Zero region first: working-offset/count arrays + colsum.
    unsigned* wsu = (unsigned*)d_ws;
    size_t off = 0;
    int* cw_qoq = (int*)(wsu + off); off += N_FM + 1;
    int* cw_cp  = (int*)(wsu + off); off += N_FM + 1;
    int* cw_rb  = (int*)(wsu + off); off += N_FM + 1;
    int* cw_bp  = (int*)(wsu + off); off += N_TP + 1;
    int* cw_cd  = (int*)(wsu + off); off += N_SM + 1;
    float* colsum = (float*)(wsu + off); off += 384;
    size_t zero_words = off;
    int* of_qoq = (int*)(wsu + off); off += N_FM + 1;
    int* of_cp  = (int*)(wsu + off); off += N_FM + 1;
    int* of_rb  = (int*)(wsu + off); off += N_FM + 1;
    int* of_bp  = (int*)(wsu + off); off += N_TP + 1;
    int* of_cd  = (int*)(wsu + off); off += N_SM + 1;
    int* so_qoq = (int*)(wsu + off); off += E_QOQ;
    int* so_bp  = (int*)(wsu + off); off += E_BP;
    int* so_cp  = (int*)(wsu + off); off += E_CP;
    int* so_cd  = (int*)(wsu + off); off += E_CD;
    int* so_rb  = (int*)(wsu + off); off += E_RB;
    unsigned* mean_qoq = wsu + off; off += (size_t)N_FM * 32;
    unsigned* mean_cp  = wsu + off; off += (size_t)N_FM * 16;
    unsigned* mean_rb  = wsu + off; off += (size_t)N_FM * 16;
    unsigned* mean_bp  = wsu + off; off += (size_t)N_TP * 32;
    unsigned* mean_cd  = wsu + off; off += (size_t)N_SM * 16;
    unsigned* pe_f     = wsu + off; off += (size_t)N_TP * 16;
    unsigned* x_fm_f   = wsu + off; off += (size_t)N_FM * 32;
    unsigned* x_sm_f   = wsu + off; off += (size_t)N_SM * 16;
    float* wr_comb     = (float*)(wsu + off); off += 64 * HID;
    unsigned* wf_fm    = wsu + off; off += 96 * HID;
    unsigned* wf_tp    = wsu + off; off += 48 * HID;
    unsigned* wf_sm    = wsu + off; off += 32 * HID;

    hipMemsetAsync(d_ws, 0, zero_words * 4, stream);

    // feature / weight packing (independent of sort)
    pe_pack_kernel<<<(N_TP * 16 + 255) / 256, 256, 0, stream>>>(pe_table, period_vol, pe_f);
    pack_x_kernel<<<(N_FM * 32 + 255) / 256, 256, 0, stream>>>(x_fm, x_fm_f, N_FM * 32);
    pack_x_kernel<<<(N_SM * 16 + 255) / 256, 256, 0, stream>>>(x_sm, x_sm_f, N_SM * 16);
    wr_comb_kernel<<<(64 * HID + 255) / 256, 256, 0, stream>>>(qoq_Wr, cp_Wr, rb_Wr, wr_comb);
    const int PW = 256;
    pack_w_kernel<<<(32 * HID + PW - 1) / PW, PW, 0, stream>>>(qoq_Wl, wf_fm, 64);
    pack_w_kernel<<<(16 * HID + PW - 1) / PW, PW, 0, stream>>>(cp_Wl, wf_fm + 32 * HID, 32);
    pack_w_kernel<<<(16 * HID + PW - 1) / PW, PW, 0, stream>>>(rb_Wl, wf_fm + 48 * HID, 32);
    pack_w_kernel<<<(32 * HID + PW - 1) / PW, PW, 0, stream>>>(wr_comb, wf_fm + 64 * HID, 64);
    pack_w_kernel<<<(32 * HID + PW - 1) / PW, PW, 0, stream>>>(bp_Wl, wf_tp, 64);
    pack_w_kernel<<<(16 * HID + PW - 1) / PW, PW, 0, stream>>>(bp_Wr, wf_tp + 32 * HID, 32);
    pack_w_kernel<<<(16 * HID + PW - 1) / PW, PW, 0, stream>>>(cd_Wl, wf_sm, 32);
    pack_w_kernel<<<(16 * HID + PW - 1) / PW, PW, 0, stream>>>(cd_Wr, wf_sm + 16 * HID, 32);

    // counting sort per relation: hist -> scan -> place
    hist_kernel<<<1024, 256, 0, stream>>>(qoq_dst, E_QOQ, cw_qoq);
    hist_kernel<<<1024, 256, 0, stream>>>(bp_dst, E_BP, cw_bp);
    hist_kernel<<<1024, 256, 0, stream>>>(cp_dst, E_CP, cw_cp);
    hist_kernel<<<1024, 256, 0, stream>>>(cd_dst, E_CD, cw_cd);
    hist_kernel<<<1024, 256, 0, stream>>>(rb_dst, E_RB, cw_rb);
    scan_kernel<<<5, 1024, 0, stream>>>(cw_qoq, of_qoq, N_FM, cw_cp, of_cp, N_FM,
                                        cw_rb, of_rb, N_FM, cw_bp, of_bp, N_TP,
                                        cw_cd, of_cd, N_SM);
    place_kernel<<<1024, 256, 0, stream>>>(qoq_src, qoq_dst, E_QOQ, cw_qoq, so_qoq);
    place_kernel<<<1024, 256, 0, stream>>>(bp_src, bp_dst, E_BP, cw_bp, so_bp);
    place_kernel<<<1024, 256, 0, stream>>>(cp_src, cp_dst, E_CP, cw_cp, so_cp);
    place_kernel<<<1024, 256, 0, stream>>>(cd_src, cd_dst, E_CD, cw_cd, so_cd);
    place_kernel<<<1024, 256, 0, stream>>>(rb_src, rb_dst, E_RB, cw_rb, so_rb);

    // gather-reduce -> packed f16 means (fp32 accumulate)
    gather_mean<5><<<(N_FM * 32 + 255) / 256, 256, 0, stream>>>(of_qoq, N_FM, so_qoq, x_fm_f, mean_qoq);
    gather_mean<5><<<(N_TP * 32 + 255) / 256, 256, 0, stream>>>(of_bp, N_TP, so_bp, x_fm_f, mean_bp);
    gather_mean<4><<<(N_FM * 16 + 255) / 256, 256, 0, stream>>>(of_cp, N_FM, so_cp, pe_f, mean_cp);
    gather_mean<4><<<(N_SM * 16 + 255) / 256, 256, 0, stream>>>(of_cd, N_SM, so_cd, pe_f, mean_cd);
    gather_mean<4><<<(N_FM * 16 + 255) / 256, 256, 0, stream>>>(of_rb, N_FM, so_rb, pe_f, mean_rb);

    // fused rows: linear + LN + relu + column-sum
    fm_rows_f16<<<2048, 128, 0, stream>>>(mean_qoq, mean_cp, mean_rb, x_fm_f, wf_fm,
                                          qoq_bl, cp_bl, rb_bl, ln_fm_g, ln_fm_b, colsum);
    rows_f16<32, 16><<<N_TP / TR, 128, 0, stream>>>(N_TP / TR, mean_bp, pe_f, wf_tp,
                                                    bp_bl, ln_tp_g, ln_tp_b, colsum + 128);
    rows_f16<16, 16><<<2048, 128, 0, stream>>>(N_SM / TR, mean_cd, x_sm_f, wf_sm,
                                               cd_bl, ln_sm_g, ln_sm_b, colsum + 256);

    head_kernel<<<1, 512, 0, stream>>>(colsum, gf, head_W1, head_b1, head_W2, head_b2,
                                       (float*)d_out);
}

// Round 8
// 1052.122 us; speedup vs baseline: 1.2421x; 1.2421x over previous
//
#include <hip/hip_runtime.h>
#include <hip/hip_fp16.h>

#define N_FM 100000
#define N_TP 4096
#define N_SM 100000
#define HID 128
#define E_QOQ 1000000
#define E_BP 1000000
#define E_CP 500000
#define E_CD 500000
#define E_RB 1000000
#define E_TOT 4000000
#define TR 32  // rows per tile

// concatenated element space: qoq | cp | rb | bp | cd
#define B_QOQ 0
#define B_CP  (N_FM)
#define B_RB  (2 * N_FM)
#define B_BP  (3 * N_FM)
#define B_CD  (3 * N_FM + N_TP)
#define NTOT  (3 * N_FM + N_TP + N_SM)
#define NB    ((NTOT + 1023) / 1024)

typedef _Float16 h2 __attribute__((ext_vector_type(2)));

#if defined(__has_builtin)
#if __has_builtin(__builtin_amdgcn_fdot2)
#define HAVE_FDOT2 1
#endif
#endif

union U32H2 { unsigned u; h2 h; };

__device__ __forceinline__ unsigned pk2(float a, float b) {
    U32H2 x; x.h = h2{(_Float16)a, (_Float16)b}; return x.u;
}
__device__ __forceinline__ float dot2(float acc, unsigned a, unsigned b) {
    U32H2 x, y; x.u = a; y.u = b;
#ifdef HAVE_FDOT2
    return __builtin_amdgcn_fdot2(x.h, y.h, acc, false);
#else
    return acc + (float)x.h[0] * (float)y.h[0] + (float)x.h[1] * (float)y.h[1];
#endif
}

// ---------------------------------------------------------------- packing kernels
__global__ void pe_pack_kernel(const float* __restrict__ pe_table, const float* __restrict__ pvol,
                               unsigned* __restrict__ pe_f) {
    int i = blockIdx.x * blockDim.x + threadIdx.x;  // pair index
    if (i < N_TP * 16) {
        float2 t = ((const float2*)pe_table)[i];
        float v = pvol[i >> 4];
        pe_f[i] = pk2(t.x * v, t.y * v);
    }
}

__global__ void pack_x_kernel(const float* __restrict__ x, unsigned* __restrict__ xp, int npairs) {
    int i = blockIdx.x * blockDim.x + threadIdx.x;
    if (i < npairs) {
        float2 t = ((const float2*)x)[i];
        xp[i] = pk2(t.x, t.y);
    }
}

__global__ void wr_comb_kernel(const float* __restrict__ a, const float* __restrict__ b,
                               const float* __restrict__ c, float* __restrict__ o) {
    int i = blockIdx.x * blockDim.x + threadIdx.x;
    if (i < 64 * HID) o[i] = a[i] + b[i] + c[i];
}

// W[K][128] fp32 -> f16 pairs [K/2][128]
__global__ void pack_w_kernel(const float* __restrict__ W, unsigned* __restrict__ dst, int K) {
    int i = blockIdx.x * blockDim.x + threadIdx.x;
    int n = (K / 2) * HID;
    if (i < n) {
        int r = i >> 7, c = i & 127;
        dst[i] = pk2(W[(2 * r) * HID + c], W[(2 * r + 1) * HID + c]);
    }
}

// ---------------------------------------------------------------- counting sort: hist -> scan(3) -> place
__global__ void hist_kernel(const int* __restrict__ dst, int nE, int* __restrict__ cnt) {
    int stride = gridDim.x * blockDim.x;
    for (int e = blockIdx.x * blockDim.x + threadIdx.x; e < nE; e += stride)
        atomicAdd(&cnt[dst[e]], 1);
}

// hierarchical scan, step 1: per-block exclusive scan + block total
__global__ void __launch_bounds__(1024) scan_local(const int* __restrict__ cnt,
                                                   int* __restrict__ offs,
                                                   int* __restrict__ bsum) {
    __shared__ int s[1024];
    const int t = threadIdx.x;
    int gid = blockIdx.x * 1024 + t;
    int v = (gid < NTOT) ? cnt[gid] : 0;
    s[t] = v;
    __syncthreads();
    for (int off = 1; off < 1024; off <<= 1) {
        int u = (t >= off) ? s[t - off] : 0;
        __syncthreads();
        s[t] += u;
        __syncthreads();
    }
    if (gid < NTOT) offs[gid] = s[t] - v;  // exclusive within block
    if (t == 1023) bsum[blockIdx.x] = s[1023];
}

// step 2: exclusive scan of block sums (NB <= 512)
__global__ void __launch_bounds__(512) scan_bsums(int* __restrict__ bsum, int* __restrict__ base) {
    __shared__ int s[512];
    const int t = threadIdx.x;
    int v = (t < NB) ? bsum[t] : 0;
    s[t] = v;
    __syncthreads();
    for (int off = 1; off < 512; off <<= 1) {
        int u = (t >= off) ? s[t - off] : 0;
        __syncthreads();
        s[t] += u;
        __syncthreads();
    }
    if (t < NB) base[t] = s[t] - v;
}

// step 3: add block base; produce final offs + working copy for place
__global__ void add_base(int* __restrict__ offs, int* __restrict__ cw,
                         const int* __restrict__ base) {
    int gid = blockIdx.x * blockDim.x + threadIdx.x;
    if (gid < NTOT) {
        int o = offs[gid] + base[gid >> 10];
        offs[gid] = o;
        cw[gid] = o;
    }
    if (gid == 0) offs[NTOT] = E_TOT;
}

__global__ void place_kernel(const int* __restrict__ src, const int* __restrict__ dst, int nE,
                             int* __restrict__ woffs, int* __restrict__ sorted_src) {
    int stride = gridDim.x * blockDim.x;
    for (int e = blockIdx.x * blockDim.x + threadIdx.x; e < nE; e += stride) {
        int p = atomicAdd(&woffs[dst[e]], 1);
        sorted_src[p] = src[e];
    }
}

// ---------------------------------------------------------------- gather-reduce: CSR -> packed f16 means
// P lanes cooperate per dst row; offs already points at this relation's slice (global edge positions)
template <int LOGP>
__global__ void gather_mean(const int* __restrict__ offs, int ndst,
                            const int* __restrict__ ssrc, const unsigned* __restrict__ feat,
                            unsigned* __restrict__ mean) {
    const int P = 1 << LOGP;
    int gid = blockIdx.x * blockDim.x + threadIdx.x;
    int g = gid >> LOGP;
    if (g >= ndst) return;
    int lane = gid & (P - 1);
    int beg = offs[g], end = offs[g + 1];
    float alo = 0.0f, ahi = 0.0f;
    int i = beg;
    for (; i + 4 <= end; i += 4) {
        int s0 = ssrc[i], s1 = ssrc[i + 1], s2 = ssrc[i + 2], s3 = ssrc[i + 3];
        unsigned v0 = feat[(size_t)s0 * P + lane];
        unsigned v1 = feat[(size_t)s1 * P + lane];
        unsigned v2 = feat[(size_t)s2 * P + lane];
        unsigned v3 = feat[(size_t)s3 * P + lane];
        U32H2 u;
        u.u = v0; alo += (float)u.h[0]; ahi += (float)u.h[1];
        u.u = v1; alo += (float)u.h[0]; ahi += (float)u.h[1];
        u.u = v2; alo += (float)u.h[0]; ahi += (float)u.h[1];
        u.u = v3; alo += (float)u.h[0]; ahi += (float)u.h[1];
    }
    for (; i < end; i++) {
        unsigned v = feat[(size_t)ssrc[i] * P + lane];
        U32H2 u; u.u = v;
        alo += (float)u.h[0]; ahi += (float)u.h[1];
    }
    float ic = (end > beg) ? 1.0f / (float)(end - beg) : 0.0f;
    mean[(size_t)g * P + lane] = pk2(alo * ic, ahi * ic);
}

// ---------------------------------------------------------------- LN + relu + colsum epilogue
__device__ __forceinline__ void ln_relu_colsum(float accv[TR], float gc, float bc,
                                               float (*s_w)[TR], float (*s_q)[TR],
                                               float& colacc, int c) {
    int wid = c >> 6;
#pragma unroll
    for (int r = 0; r < TR; r++) {
        float s = accv[r], q = accv[r] * accv[r];
#pragma unroll
        for (int off = 1; off < 64; off <<= 1) {
            s += __shfl_xor(s, off);
            q += __shfl_xor(q, off);
        }
        if ((c & 63) == 0) { s_w[wid][r] = s; s_q[wid][r] = q; }
    }
    __syncthreads();
#pragma unroll
    for (int r = 0; r < TR; r++) {
        float tot = s_w[0][r] + s_w[1][r], totq = s_q[0][r] + s_q[1][r];
        float mu = tot * (1.0f / 128.0f);
        float var = fmaxf(totq * (1.0f / 128.0f) - mu * mu, 0.0f);
        float y = (accv[r] - mu) * rsqrtf(var + 1e-5f) * gc + bc;
        colacc += fmaxf(y, 0.0f);
    }
    __syncthreads();
}

// ---------------------------------------------------------------- fm rows (f16 packed means, fdot2)
// s_in pair layout: [0..31]=qoq mean | [32..47]=cp mean | [48..63]=rb mean | [64..95]=x_fm
__global__ void __launch_bounds__(128, 3)
fm_rows_f16(const unsigned* __restrict__ mean_qoq, const unsigned* __restrict__ mean_cp,
            const unsigned* __restrict__ mean_rb, const unsigned* __restrict__ x_fm_f,
            const unsigned* __restrict__ wf,
            const float* __restrict__ bl_q, const float* __restrict__ bl_c,
            const float* __restrict__ bl_r,
            const float* __restrict__ ln_g, const float* __restrict__ ln_b,
            float* __restrict__ colsum) {
    const int c = threadIdx.x;  // 0..127
    __shared__ __align__(16) unsigned s_in[TR][96];
    __shared__ float s_w[2][TR], s_q[2][TR];
    const float bias = bl_q[c] + bl_c[c] + bl_r[c];
    const float gc = ln_g[c], bc = ln_b[c];
    float colacc = 0.0f;
    const int ntiles = N_FM / TR;
    for (int tile = blockIdx.x; tile < ntiles; tile += gridDim.x) {
        const size_t row0 = (size_t)tile * TR;
        for (int i = c; i < TR * 8; i += 128) {
            int r = i >> 3;
            *(uint4*)&s_in[r][(i & 7) * 4] = ((const uint4*)mean_qoq)[row0 * 8 + i];
        }
        for (int i = c; i < TR * 4; i += 128) {
            int r = i >> 2;
            *(uint4*)&s_in[r][32 + (i & 3) * 4] = ((const uint4*)mean_cp)[row0 * 4 + i];
        }
        for (int i = c; i < TR * 4; i += 128) {
            int r = i >> 2;
            *(uint4*)&s_in[r][48 + (i & 3) * 4] = ((const uint4*)mean_rb)[row0 * 4 + i];
        }
        for (int i = c; i < TR * 8; i += 128) {
            int r = i >> 3;
            *(uint4*)&s_in[r][64 + (i & 7) * 4] = ((const uint4*)x_fm_f)[row0 * 8 + i];
        }
        __syncthreads();
        float accv[TR];
#pragma unroll
        for (int r = 0; r < TR; r++) accv[r] = 0.0f;
        for (int p = 0; p < 96; p += 4) {
            unsigned w0 = wf[(p + 0) * HID + c], w1 = wf[(p + 1) * HID + c];
            unsigned w2 = wf[(p + 2) * HID + c], w3 = wf[(p + 3) * HID + c];
#pragma unroll
            for (int r = 0; r < TR; r++) {
                uint4 v = *(const uint4*)&s_in[r][p];
                accv[r] = dot2(dot2(dot2(dot2(accv[r], v.x, w0), v.y, w1), v.z, w2), v.w, w3);
            }
        }
#pragma unroll
        for (int r = 0; r < TR; r++) accv[r] = (accv[r] + bias) * (1.0f / 3.0f);
        ln_relu_colsum(accv, gc, bc, s_w, s_q, colacc, c);
    }
    unsafeAtomicAdd(&colsum[c], colacc);
}

// ---------------------------------------------------------------- generic rows (f16 packed means)
template <int PA, int PB>
__global__ void __launch_bounds__(128, 3)
rows_f16(int ntiles, const unsigned* __restrict__ meanA, const unsigned* __restrict__ xB,
         const unsigned* __restrict__ wf, const float* __restrict__ bl,
         const float* __restrict__ ln_g, const float* __restrict__ ln_b,
         float* __restrict__ colsum) {
    const int c = threadIdx.x;  // 0..127
    __shared__ __align__(16) unsigned s_in[TR][PA + PB];
    __shared__ float s_w[2][TR], s_q[2][TR];
    const float bias = bl[c];
    const float gc = ln_g[c], bc = ln_b[c];
    float colacc = 0.0f;
    const int A4 = PA / 4, B4 = PB / 4;
    for (int tile = blockIdx.x; tile < ntiles; tile += gridDim.x) {
        const size_t row0 = (size_t)tile * TR;
        for (int i = c; i < TR * A4; i += 128) {
            int r = i / A4, q = i % A4;
            *(uint4*)&s_in[r][q * 4] = ((const uint4*)meanA)[row0 * A4 + i];
        }
        for (int i = c; i < TR * B4; i += 128) {
            int r = i / B4, q = i % B4;
            *(uint4*)&s_in[r][PA + q * 4] = ((const uint4*)xB)[row0 * B4 + i];
        }
        __syncthreads();
        float accv[TR];
#pragma unroll
        for (int r = 0; r < TR; r++) accv[r] = 0.0f;
        for (int p = 0; p < PA + PB; p += 4) {
            unsigned w0 = wf[(p + 0) * HID + c], w1 = wf[(p + 1) * HID + c];
            unsigned w2 = wf[(p + 2) * HID + c], w3 = wf[(p + 3) * HID + c];
#pragma unroll
            for (int r = 0; r < TR; r++) {
                uint4 v = *(const uint4*)&s_in[r][p];
                accv[r] = dot2(dot2(dot2(dot2(accv[r], v.x, w0), v.y, w1), v.z, w2), v.w, w3);
            }
        }
#pragma unroll
        for (int r = 0; r < TR; r++) accv[r] += bias;
        ln_relu_colsum(accv, gc, bc, s_w, s_q, colacc, c);
    }
    unsafeAtomicAdd(&colsum[c], colacc);
}

// ---------------------------------------------------------------- head MLP -> scalar
__global__ void head_kernel(const float* __restrict__ colsum, const float* __restrict__ gf,
                            const float* __restrict__ W1, const float* __restrict__ b1,
                            const float* __restrict__ W2, const float* __restrict__ b2,
                            float* __restrict__ out) {
    __shared__ float h[448];
    __shared__ float h1[64];
    int t = threadIdx.x;  // 512 threads
    if (t < 128) h[t] = colsum[t] * (1.0f / N_FM);
    else if (t < 256) h[t] = colsum[t] * (1.0f / N_TP);
    else if (t < 384) h[t] = colsum[t] * (1.0f / N_SM);
    else if (t < 448) h[t] = gf[t - 384];
    __syncthreads();
    if (t < 64) {
        float a = b1[t];
        for (int k = 0; k < 448; k++) a += h[k] * W1[k * 64 + t];
        h1[t] = fmaxf(a, 0.0f);
    }
    __syncthreads();
    if (t < 64) {
        float p = h1[t] * W2[t];
#pragma unroll
        for (int off = 1; off < 64; off <<= 1) p += __shfl_xor(p, off);
        if (t == 0) out[0] = p + b2[0];
    }
}

extern "C" void kernel_launch(void* const* d_in, const int* in_sizes, int n_in,
                              void* d_out, int out_size, void* d_ws, size_t ws_size,
                              hipStream_t stream) {
    const float* x_fm = (const float*)d_in[0];
    const float* x_sm = (const float*)d_in[1];
    const float* period_vol = (const float*)d_in[2];
    const float* gf = (const float*)d_in[3];
    const float* pe_table = (const float*)d_in[4];
    const int* qoq_src = (const int*)d_in[5];
    const int* qoq_dst = (const int*)d_in[6];
    const int* bp_src = (const int*)d_in[7];
    const int* bp_dst = (const int*)d_in[8];
    const int* cp_src = (const int*)d_in[9];
    const int* cp_dst = (const int*)d_in[10];
    const int* cd_src = (const int*)d_in[11];
    const int* cd_dst = (const int*)d_in[12];
    const int* rb_src = (const int*)d_in[13];
    const int* rb_dst = (const int*)d_in[14];
    const float* qoq_Wl = (const float*)d_in[15];
    const float* qoq_bl = (const float*)d_in[16];
    const float* qoq_Wr = (const float*)d_in[17];
    const float* bp_Wl = (const float*)d_in[18];
    const float* bp_bl = (const float*)d_in[19];
    const float* bp_Wr = (const float*)d_in[20];
    const float* cp_Wl = (const float*)d_in[21];
    const float* cp_bl = (const float*)d_in[22];
    const float* cp_Wr = (const float*)d_in[23];
    const float* cd_Wl = (const float*)d_in[24];
    const float* cd_bl = (const float*)d_in[25];
    const float* cd_Wr = (const float*)d_in[26];
    const float* rb_Wl = (const float*)d_in[27];
    const float* rb_bl = (const float*)d_in[28];
    const float* rb_Wr = (const float*)d_in[29];
    const float* ln_fm_g = (const float*)d_in[30];
    const float* ln_fm_b = (const float*)d_in[31];
    const float* ln_tp_g = (const float*)d_in[32];
    const float* ln_tp_b = (const float*)d_in[33];
    const float* ln_sm_g = (const float*)d_in[34];
    const float* ln_sm_b = (const float*)d_in[35];
    const float* head_W1 = (const float*)d_in[36];
    const float* head_b1 = (const float*)d_in[37];
    const float* head_W2 = (const float*)d_in[38];
    const float* head_b2 = (const float*)d_in[39];

    // workspace layout (4-byte words). Zero region: combined counts + colsum.
    unsigned* wsu = (unsigned*)d_ws;
    size_t off = 0;
    int* cw = (int*)(wsu + off); off += NTOT;          // combined count/working-offset array
    float* colsum = (float*)(wsu + off); off += 384;
    size_t zero_words = off;
    int* offs = (int*)(wsu + off); off += NTOT + 1;    // global CSR offsets
    int* bsum = (int*)(wsu + off); off += NB;
    int* base = (int*)(wsu + off); off += NB;
    int* so_all = (int*)(wsu + off); off += E_TOT;     // sorted src, all relations
    unsigned* mean_qoq = wsu + off; off += (size_t)N_FM * 32;
    unsigned* mean_cp  = wsu + off; off += (size_t)N_FM * 16;
    unsigned* mean_rb  = wsu + off; off += (size_t)N_FM * 16;
    unsigned* mean_bp  = wsu + off; off += (size_t)N_TP * 32;
    unsigned* mean_cd  = wsu + off; off += (size_t)N_SM * 16;
    unsigned* pe_f     = wsu + off; off += (size_t)N_TP * 16;
    unsigned* x_fm_f   = wsu + off; off += (size_t)N_FM * 32;
    unsigned* x_sm_f   = wsu + off; off += (size_t)N_SM * 16;
    float* wr_comb     = (float*)(wsu + off); off += 64 * HID;
    unsigned* wf_fm    = wsu + off; off += 96 * HID;
    unsigned* wf_tp    = wsu + off; off += 48 * HID;
    unsigned* wf_sm    = wsu + off; off += 32 * HID;

    hipMemsetAsync(d_ws, 0, zero_words * 4, stream);

    // feature / weight packing (independent of sort)
    pe_pack_kernel<<<(N_TP * 16 + 255) / 256, 256, 0, stream>>>(pe_table, period_vol, pe_f);
    pack_x_kernel<<<(N_FM * 32 + 255) / 256, 256, 0, stream>>>(x_fm, x_fm_f, N_FM * 32);
    pack_x_kernel<<<(N_SM * 16 + 255) / 256, 256, 0, stream>>>(x_sm, x_sm_f, N_SM * 16);
    wr_comb_kernel<<<(64 * HID + 255) / 256, 256, 0, stream>>>(qoq_Wr, cp_Wr, rb_Wr, wr_comb);
    const int PW = 256;
    pack_w_kernel<<<(32 * HID + PW - 1) / PW, PW, 0, stream>>>(qoq_Wl, wf_fm, 64);
    pack_w_kernel<<<(16 * HID + PW - 1) / PW, PW, 0, stream>>>(cp_Wl, wf_fm + 32 * HID, 32);
    pack_w_kernel<<<(16 * HID + PW - 1) / PW, PW, 0, stream>>>(rb_Wl, wf_fm + 48 * HID, 32);
    pack_w_kernel<<<(32 * HID + PW - 1) / PW, PW, 0, stream>>>(wr_comb, wf_fm + 64 * HID, 64);
    pack_w_kernel<<<(32 * HID + PW - 1) / PW, PW, 0, stream>>>(bp_Wl, wf_tp, 64);
    pack_w_kernel<<<(16 * HID + PW - 1) / PW, PW, 0, stream>>>(bp_Wr, wf_tp + 32 * HID, 32);
    pack_w_kernel<<<(16 * HID + PW - 1) / PW, PW, 0, stream>>>(cd_Wl, wf_sm, 32);
    pack_w_kernel<<<(16 * HID + PW - 1) / PW, PW, 0, stream>>>(cd_Wr, wf_sm + 16 * HID, 32);

    // counting sort: hist (into concatenated element space) -> 3-phase scan -> place
    hist_kernel<<<1024, 256, 0, stream>>>(qoq_dst, E_QOQ, cw + B_QOQ);
    hist_kernel<<<1024, 256, 0, stream>>>(cp_dst, E_CP, cw + B_CP);
    hist_kernel<<<1024, 256, 0, stream>>>(rb_dst, E_RB, cw + B_RB);
    hist_kernel<<<1024, 256, 0, stream>>>(bp_dst, E_BP, cw + B_BP);
    hist_kernel<<<1024, 256, 0, stream>>>(cd_dst, E_CD, cw + B_CD);
    scan_local<<<NB, 1024, 0, stream>>>(cw, offs, bsum);
    scan_bsums<<<1, 512, 0, stream>>>(bsum, base);
    add_base<<<(NTOT + 255) / 256, 256, 0, stream>>>(offs, cw, base);
    place_kernel<<<1024, 256, 0, stream>>>(qoq_src, qoq_dst, E_QOQ, cw + B_QOQ, so_all);
    place_kernel<<<1024, 256, 0, stream>>>(cp_src, cp_dst, E_CP, cw + B_CP, so_all);
    place_kernel<<<1024, 256, 0, stream>>>(rb_src, rb_dst, E_RB, cw + B_RB, so_all);
    place_kernel<<<1024, 256, 0, stream>>>(bp_src, bp_dst, E_BP, cw + B_BP, so_all);
    place_kernel<<<1024, 256, 0, stream>>>(cd_src, cd_dst, E_CD, cw + B_CD, so_all);

    // gather-reduce -> packed f16 means (fp32 accumulate)
    gather_mean<5><<<(N_FM * 32 + 255) / 256, 256, 0, stream>>>(offs + B_QOQ, N_FM, so_all, x_fm_f, mean_qoq);
    gather_mean<5><<<(N_TP * 32 + 255) / 256, 256, 0, stream>>>(offs + B_BP, N_TP, so_all, x_fm_f, mean_bp);
    gather_mean<4><<<(N_FM * 16 + 255) / 256, 256, 0, stream>>>(offs + B_CP, N_FM, so_all, pe_f, mean_cp);
    gather_mean<4><<<(N_SM * 16 + 255) / 256, 256, 0, stream>>>(offs + B_CD, N_SM, so_all, pe_f, mean_cd);
    gather_mean<4><<<(N_FM * 16 + 255) / 256, 256, 0, stream>>>(offs + B_RB, N_FM, so_all, pe_f, mean_rb);

    // fused rows: linear + LN + relu + column-sum
    fm_rows_f16<<<2048, 128, 0, stream>>>(mean_qoq, mean_cp, mean_rb, x_fm_f, wf_fm,
                                          qoq_bl, cp_bl, rb_bl, ln_fm_g, ln_fm_b, colsum);
    rows_f16<32, 16><<<N_TP / TR, 128, 0, stream>>>(N_TP / TR, mean_bp, pe_f, wf_tp,
                                                    bp_bl, ln_tp_g, ln_tp_b, colsum + 128);
    rows_f16<16, 16><<<2048, 128, 0, stream>>>(N_SM / TR, mean_cd, x_sm_f, wf_sm,
                                               cd_bl, ln_sm_g, ln_sm_b, colsum + 256);

    head_kernel<<<1, 512, 0, stream>>>(colsum, gf, head_W1, head_b1, head_W2, head_b2,
                                       (float*)d_out);
}

// Round 9
// 1005.168 us; speedup vs baseline: 1.3001x; 1.0467x over previous
//
#include <hip/hip_runtime.h>
#include <hip/hip_fp16.h>

#define N_FM 100000
#define N_TP 4096
#define N_SM 100000
#define HID 128
#define E_QOQ 1000000
#define E_BP 1000000
#define E_CP 500000
#define E_CD 500000
#define E_RB 1000000
#define E_TOT 4000000
#define TR 32  // rows per tile

// concatenated element space: qoq | cp | rb | bp | cd
#define B_QOQ 0
#define B_CP  (N_FM)
#define B_RB  (2 * N_FM)
#define B_BP  (3 * N_FM)
#define B_CD  (3 * N_FM + N_TP)
#define NTOT  (3 * N_FM + N_TP + N_SM)
#define NB    ((NTOT + 1023) / 1024)

typedef _Float16 h2 __attribute__((ext_vector_type(2)));

#if defined(__has_builtin)
#if __has_builtin(__builtin_amdgcn_fdot2)
#define HAVE_FDOT2 1
#endif
#endif

union U32H2 { unsigned u; h2 h; };

__device__ __forceinline__ unsigned pk2(float a, float b) {
    U32H2 x; x.h = h2{(_Float16)a, (_Float16)b}; return x.u;
}
__device__ __forceinline__ float dot2(float acc, unsigned a, unsigned b) {
    U32H2 x, y; x.u = a; y.u = b;
#ifdef HAVE_FDOT2
    return __builtin_amdgcn_fdot2(x.h, y.h, acc, false);
#else
    return acc + (float)x.h[0] * (float)y.h[0] + (float)x.h[1] * (float)y.h[1];
#endif
}

// ---------------------------------------------------------------- unified pack kernel
// ranges: x_fm pairs | x_sm | pe | qoq_Wl | cp_Wl | rb_Wl | Wr-sum | bp_Wl | bp_Wr | cd_Wl | cd_Wr
#define R1 (N_FM * 32)
#define R2 (R1 + N_SM * 16)
#define R3 (R2 + N_TP * 16)
#define R4 (R3 + 32 * HID)
#define R5 (R4 + 16 * HID)
#define R6 (R5 + 16 * HID)
#define R7 (R6 + 32 * HID)
#define R8 (R7 + 32 * HID)
#define R9 (R8 + 16 * HID)
#define R10 (R9 + 16 * HID)
#define R11 (R10 + 16 * HID)

__device__ __forceinline__ void pack_w_elem(const float* W, unsigned* dst, int j) {
    int rr = j >> 7, c = j & 127;
    dst[j] = pk2(W[(2 * rr) * HID + c], W[(2 * rr + 1) * HID + c]);
}

__global__ void pack_all(const float* __restrict__ x_fm, const float* __restrict__ x_sm,
                         const float* __restrict__ pe_table, const float* __restrict__ pvol,
                         const float* __restrict__ qoq_Wl, const float* __restrict__ cp_Wl,
                         const float* __restrict__ rb_Wl, const float* __restrict__ qoq_Wr,
                         const float* __restrict__ cp_Wr, const float* __restrict__ rb_Wr,
                         const float* __restrict__ bp_Wl, const float* __restrict__ bp_Wr,
                         const float* __restrict__ cd_Wl, const float* __restrict__ cd_Wr,
                         unsigned* __restrict__ x_fm_f, unsigned* __restrict__ x_sm_f,
                         unsigned* __restrict__ pe_f, unsigned* __restrict__ wf_fm,
                         unsigned* __restrict__ wf_tp, unsigned* __restrict__ wf_sm) {
    int gid = blockIdx.x * blockDim.x + threadIdx.x;
    if (gid < R1) {
        float2 t = ((const float2*)x_fm)[gid];
        x_fm_f[gid] = pk2(t.x, t.y);
    } else if (gid < R2) {
        int i = gid - R1;
        float2 t = ((const float2*)x_sm)[i];
        x_sm_f[i] = pk2(t.x, t.y);
    } else if (gid < R3) {
        int i = gid - R2;
        float2 t = ((const float2*)pe_table)[i];
        float v = pvol[i >> 4];
        pe_f[i] = pk2(t.x * v, t.y * v);
    } else if (gid < R4) {
        pack_w_elem(qoq_Wl, wf_fm, gid - R3);
    } else if (gid < R5) {
        pack_w_elem(cp_Wl, wf_fm + 32 * HID, gid - R4);
    } else if (gid < R6) {
        pack_w_elem(rb_Wl, wf_fm + 48 * HID, gid - R5);
    } else if (gid < R7) {
        int j = gid - R6;
        int rr = j >> 7, c = j & 127;
        float a0 = qoq_Wr[(2 * rr) * HID + c] + cp_Wr[(2 * rr) * HID + c] + rb_Wr[(2 * rr) * HID + c];
        float a1 = qoq_Wr[(2 * rr + 1) * HID + c] + cp_Wr[(2 * rr + 1) * HID + c] + rb_Wr[(2 * rr + 1) * HID + c];
        wf_fm[64 * HID + j] = pk2(a0, a1);
    } else if (gid < R8) {
        pack_w_elem(bp_Wl, wf_tp, gid - R7);
    } else if (gid < R9) {
        pack_w_elem(bp_Wr, wf_tp + 32 * HID, gid - R8);
    } else if (gid < R10) {
        pack_w_elem(cd_Wl, wf_sm, gid - R9);
    } else if (gid < R11) {
        pack_w_elem(cd_Wr, wf_sm + 16 * HID, gid - R10);
    }
}

// ---------------------------------------------------------------- unified hist / place
__global__ void hist_all(const int* __restrict__ qoq_dst, const int* __restrict__ cp_dst,
                         const int* __restrict__ rb_dst, const int* __restrict__ bp_dst,
                         const int* __restrict__ cd_dst, int* __restrict__ cw) {
    int e = blockIdx.x * blockDim.x + threadIdx.x;
    if (e >= E_TOT) return;
    int b, d;
    if (e < E_QOQ) { b = B_QOQ; d = qoq_dst[e]; }
    else if (e < E_QOQ + E_CP) { b = B_CP; d = cp_dst[e - E_QOQ]; }
    else if (e < E_QOQ + E_CP + E_RB) { b = B_RB; d = rb_dst[e - E_QOQ - E_CP]; }
    else if (e < E_QOQ + E_CP + E_RB + E_BP) { b = B_BP; d = bp_dst[e - E_QOQ - E_CP - E_RB]; }
    else { b = B_CD; d = cd_dst[e - E_QOQ - E_CP - E_RB - E_BP]; }
    atomicAdd(&cw[b + d], 1);
}

__global__ void place_all(const int* __restrict__ qoq_src, const int* __restrict__ qoq_dst,
                          const int* __restrict__ cp_src, const int* __restrict__ cp_dst,
                          const int* __restrict__ rb_src, const int* __restrict__ rb_dst,
                          const int* __restrict__ bp_src, const int* __restrict__ bp_dst,
                          const int* __restrict__ cd_src, const int* __restrict__ cd_dst,
                          int* __restrict__ cw, int* __restrict__ so_all) {
    int e = blockIdx.x * blockDim.x + threadIdx.x;
    if (e >= E_TOT) return;
    int b, d, s;
    if (e < E_QOQ) { b = B_QOQ; d = qoq_dst[e]; s = qoq_src[e]; }
    else if (e < E_QOQ + E_CP) { int i = e - E_QOQ; b = B_CP; d = cp_dst[i]; s = cp_src[i]; }
    else if (e < E_QOQ + E_CP + E_RB) { int i = e - E_QOQ - E_CP; b = B_RB; d = rb_dst[i]; s = rb_src[i]; }
    else if (e < E_QOQ + E_CP + E_RB + E_BP) { int i = e - E_QOQ - E_CP - E_RB; b = B_BP; d = bp_dst[i]; s = bp_src[i]; }
    else { int i = e - E_QOQ - E_CP - E_RB - E_BP; b = B_CD; d = cd_dst[i]; s = cd_src[i]; }
    int p = atomicAdd(&cw[b + d], 1);
    so_all[p] = s;
}

// ---------------------------------------------------------------- hierarchical scan
__global__ void __launch_bounds__(1024) scan_local(const int* __restrict__ cnt,
                                                   int* __restrict__ offs,
                                                   int* __restrict__ bsum) {
    __shared__ int s[1024];
    const int t = threadIdx.x;
    int gid = blockIdx.x * 1024 + t;
    int v = (gid < NTOT) ? cnt[gid] : 0;
    s[t] = v;
    __syncthreads();
    for (int off = 1; off < 1024; off <<= 1) {
        int u = (t >= off) ? s[t - off] : 0;
        __syncthreads();
        s[t] += u;
        __syncthreads();
    }
    if (gid < NTOT) offs[gid] = s[t] - v;
    if (t == 1023) bsum[blockIdx.x] = s[1023];
}

__global__ void __launch_bounds__(512) scan_bsums(int* __restrict__ bsum, int* __restrict__ base) {
    __shared__ int s[512];
    const int t = threadIdx.x;
    int v = (t < NB) ? bsum[t] : 0;
    s[t] = v;
    __syncthreads();
    for (int off = 1; off < 512; off <<= 1) {
        int u = (t >= off) ? s[t - off] : 0;
        __syncthreads();
        s[t] += u;
        __syncthreads();
    }
    if (t < NB) base[t] = s[t] - v;
}

__global__ void add_base(int* __restrict__ offs, int* __restrict__ cw,
                         const int* __restrict__ base) {
    int gid = blockIdx.x * blockDim.x + threadIdx.x;
    if (gid < NTOT) {
        int o = offs[gid] + base[gid >> 10];
        offs[gid] = o;
        cw[gid] = o;
    }
    if (gid == 0) offs[NTOT] = E_TOT;
}

// ---------------------------------------------------------------- unified gather
template <int LOGP>
__device__ __forceinline__ void gather_one(int g, int lane, const int* __restrict__ offs,
                                           const int* __restrict__ ssrc,
                                           const unsigned* __restrict__ feat,
                                           unsigned* __restrict__ mean) {
    const int P = 1 << LOGP;
    int beg = offs[g], end = offs[g + 1];
    float alo = 0.0f, ahi = 0.0f;
    int i = beg;
    for (; i + 4 <= end; i += 4) {
        int s0 = ssrc[i], s1 = ssrc[i + 1], s2 = ssrc[i + 2], s3 = ssrc[i + 3];
        unsigned v0 = feat[(size_t)s0 * P + lane];
        unsigned v1 = feat[(size_t)s1 * P + lane];
        unsigned v2 = feat[(size_t)s2 * P + lane];
        unsigned v3 = feat[(size_t)s3 * P + lane];
        U32H2 u;
        u.u = v0; alo += (float)u.h[0]; ahi += (float)u.h[1];
        u.u = v1; alo += (float)u.h[0]; ahi += (float)u.h[1];
        u.u = v2; alo += (float)u.h[0]; ahi += (float)u.h[1];
        u.u = v3; alo += (float)u.h[0]; ahi += (float)u.h[1];
    }
    for (; i < end; i++) {
        unsigned v = feat[(size_t)ssrc[i] * P + lane];
        U32H2 u; u.u = v;
        alo += (float)u.h[0]; ahi += (float)u.h[1];
    }
    float ic = (end > beg) ? 1.0f / (float)(end - beg) : 0.0f;
    mean[(size_t)g * P + lane] = pk2(alo * ic, ahi * ic);
}

// ranges (bp first: its long per-dst chains start earliest)
#define G1 (N_TP * 32)
#define G2 (G1 + N_FM * 32)
#define G3 (G2 + N_FM * 16)
#define G4 (G3 + N_SM * 16)
#define G5 (G4 + N_FM * 16)

__global__ void gather_all(const int* __restrict__ offs, const int* __restrict__ so_all,
                           const unsigned* __restrict__ x_fm_f, const unsigned* __restrict__ pe_f,
                           unsigned* __restrict__ mean_qoq, unsigned* __restrict__ mean_cp,
                           unsigned* __restrict__ mean_rb, unsigned* __restrict__ mean_bp,
                           unsigned* __restrict__ mean_cd) {
    int gid = blockIdx.x * blockDim.x + threadIdx.x;
    if (gid < G1) {
        gather_one<5>(gid >> 5, gid & 31, offs + B_BP, so_all, x_fm_f, mean_bp);
    } else if (gid < G2) {
        int i = gid - G1;
        gather_one<5>(i >> 5, i & 31, offs + B_QOQ, so_all, x_fm_f, mean_qoq);
    } else if (gid < G3) {
        int i = gid - G2;
        gather_one<4>(i >> 4, i & 15, offs + B_CP, so_all, pe_f, mean_cp);
    } else if (gid < G4) {
        int i = gid - G3;
        gather_one<4>(i >> 4, i & 15, offs + B_CD, so_all, pe_f, mean_cd);
    } else if (gid < G5) {
        int i = gid - G4;
        gather_one<4>(i >> 4, i & 15, offs + B_RB, so_all, pe_f, mean_rb);
    }
}

// ---------------------------------------------------------------- fm rows: 2 cols/thread, rows split across waves
// s_in pair layout: [0..31]=qoq | [32..47]=cp | [48..63]=rb | [64..95]=x_fm; stride 100 (bank-stagger)
__global__ void __launch_bounds__(128, 4)
fm_rows2(const unsigned* __restrict__ mean_qoq, const unsigned* __restrict__ mean_cp,
         const unsigned* __restrict__ mean_rb, const unsigned* __restrict__ x_fm_f,
         const unsigned* __restrict__ wf,
         const float* __restrict__ bl_q, const float* __restrict__ bl_c,
         const float* __restrict__ bl_r,
         const float* __restrict__ ln_g, const float* __restrict__ ln_b,
         float* __restrict__ colsum) {
    const int tid = threadIdx.x;
    const int lane = tid & 63, wave = tid >> 6;
    const int rbase = wave * 16;
    __shared__ __align__(16) unsigned s_in[TR][100];
    const float bias0 = bl_q[lane] + bl_c[lane] + bl_r[lane];
    const float bias1 = bl_q[lane + 64] + bl_c[lane + 64] + bl_r[lane + 64];
    const float g0 = ln_g[lane], b0 = ln_b[lane];
    const float g1 = ln_g[lane + 64], b1 = ln_b[lane + 64];
    float colacc0 = 0.0f, colacc1 = 0.0f;
    const int ntiles = N_FM / TR;
    for (int tile = blockIdx.x; tile < ntiles; tile += gridDim.x) {
        const size_t row0 = (size_t)tile * TR;
        for (int i = tid; i < TR * 8; i += 128) {
            int r = i >> 3;
            *(uint4*)&s_in[r][(i & 7) * 4] = ((const uint4*)mean_qoq)[row0 * 8 + i];
        }
        for (int i = tid; i < TR * 4; i += 128) {
            int r = i >> 2;
            *(uint4*)&s_in[r][32 + (i & 3) * 4] = ((const uint4*)mean_cp)[row0 * 4 + i];
        }
        for (int i = tid; i < TR * 4; i += 128) {
            int r = i >> 2;
            *(uint4*)&s_in[r][48 + (i & 3) * 4] = ((const uint4*)mean_rb)[row0 * 4 + i];
        }
        for (int i = tid; i < TR * 8; i += 128) {
            int r = i >> 3;
            *(uint4*)&s_in[r][64 + (i & 7) * 4] = ((const uint4*)x_fm_f)[row0 * 8 + i];
        }
        __syncthreads();
        float a0[16], a1[16];
#pragma unroll
        for (int r = 0; r < 16; r++) { a0[r] = 0.0f; a1[r] = 0.0f; }
        for (int p = 0; p < 96; p += 4) {
            unsigned w00 = wf[(p + 0) * HID + lane], w01 = wf[(p + 1) * HID + lane];
            unsigned w02 = wf[(p + 2) * HID + lane], w03 = wf[(p + 3) * HID + lane];
            unsigned w10 = wf[(p + 0) * HID + lane + 64], w11 = wf[(p + 1) * HID + lane + 64];
            unsigned w12 = wf[(p + 2) * HID + lane + 64], w13 = wf[(p + 3) * HID + lane + 64];
#pragma unroll
            for (int r = 0; r < 16; r++) {
                uint4 v = *(const uint4*)&s_in[rbase + r][p];
                a0[r] = dot2(dot2(dot2(dot2(a0[r], v.x, w00), v.y, w01), v.z, w02), v.w, w03);
                a1[r] = dot2(dot2(dot2(dot2(a1[r], v.x, w10), v.y, w11), v.z, w12), v.w, w13);
            }
        }
#pragma unroll
        for (int r = 0; r < 16; r++) {
            float y0 = (a0[r] + bias0) * (1.0f / 3.0f);
            float y1 = (a1[r] + bias1) * (1.0f / 3.0f);
            float s = y0 + y1, q = y0 * y0 + y1 * y1;
#pragma unroll
            for (int off = 1; off < 64; off <<= 1) {
                s += __shfl_xor(s, off);
                q += __shfl_xor(q, off);
            }
            float mu = s * (1.0f / 128.0f);
            float var = fmaxf(q * (1.0f / 128.0f) - mu * mu, 0.0f);
            float rs = rsqrtf(var + 1e-5f);
            colacc0 += fmaxf((y0 - mu) * rs * g0 + b0, 0.0f);
            colacc1 += fmaxf((y1 - mu) * rs * g1 + b1, 0.0f);
        }
        __syncthreads();
    }
    unsafeAtomicAdd(&colsum[lane], colacc0);
    unsafeAtomicAdd(&colsum[lane + 64], colacc1);
}

// ---------------------------------------------------------------- generic rows, 2 cols/thread
template <int PA, int PB>
__global__ void __launch_bounds__(128, 4)
rows2(int ntiles, const unsigned* __restrict__ meanA, const unsigned* __restrict__ xB,
      const unsigned* __restrict__ wf, const float* __restrict__ bl,
      const float* __restrict__ ln_g, const float* __restrict__ ln_b,
      float* __restrict__ colsum) {
    const int tid = threadIdx.x;
    const int lane = tid & 63, wave = tid >> 6;
    const int rbase = wave * 16;
    __shared__ __align__(16) unsigned s_in[TR][PA + PB + 4];
    const float bias0 = bl[lane], bias1 = bl[lane + 64];
    const float g0 = ln_g[lane], b0 = ln_b[lane];
    const float g1 = ln_g[lane + 64], b1 = ln_b[lane + 64];
    float colacc0 = 0.0f, colacc1 = 0.0f;
    const int A4 = PA / 4, B4 = PB / 4;
    for (int tile = blockIdx.x; tile < ntiles; tile += gridDim.x) {
        const size_t row0 = (size_t)tile * TR;
        for (int i = tid; i < TR * A4; i += 128) {
            int r = i / A4, q = i % A4;
            *(uint4*)&s_in[r][q * 4] = ((const uint4*)meanA)[row0 * A4 + i];
        }
        for (int i = tid; i < TR * B4; i += 128) {
            int r = i / B4, q = i % B4;
            *(uint4*)&s_in[r][PA + q * 4] = ((const uint4*)xB)[row0 * B4 + i];
        }
        __syncthreads();
        float a0[16], a1[16];
#pragma unroll
        for (int r = 0; r < 16; r++) { a0[r] = 0.0f; a1[r] = 0.0f; }
        for (int p = 0; p < PA + PB; p += 4) {
            unsigned w00 = wf[(p + 0) * HID + lane], w01 = wf[(p + 1) * HID + lane];
            unsigned w02 = wf[(p + 2) * HID + lane], w03 = wf[(p + 3) * HID + lane];
            unsigned w10 = wf[(p + 0) * HID + lane + 64], w11 = wf[(p + 1) * HID + lane + 64];
            unsigned w12 = wf[(p + 2) * HID + lane + 64], w13 = wf[(p + 3) * HID + lane + 64];
#pragma unroll
            for (int r = 0; r < 16; r++) {
                uint4 v = *(const uint4*)&s_in[rbase + r][p];
                a0[r] = dot2(dot2(dot2(dot2(a0[r], v.x, w00), v.y, w01), v.z, w02), v.w, w03);
                a1[r] = dot2(dot2(dot2(dot2(a1[r], v.x, w10), v.y, w11), v.z, w12), v.w, w13);
            }
        }
#pragma unroll
        for (int r = 0; r < 16; r++) {
            float y0 = a0[r] + bias0;
            float y1 = a1[r] + bias1;
            float s = y0 + y1, q = y0 * y0 + y1 * y1;
#pragma unroll
            for (int off = 1; off < 64; off <<= 1) {
                s += __shfl_xor(s, off);
                q += __shfl_xor(q, off);
            }
            float mu = s * (1.0f / 128.0f);
            float var = fmaxf(q * (1.0f / 128.0f) - mu * mu, 0.0f);
            float rs = rsqrtf(var + 1e-5f);
            colacc0 += fmaxf((y0 - mu) * rs * g0 + b0, 0.0f);
            colacc1 += fmaxf((y1 - mu) * rs * g1 + b1, 0.0f);
        }
        __syncthreads();
    }
    unsafeAtomicAdd(&colsum[lane], colacc0);
    unsafeAtomicAdd(&colsum[lane + 64], colacc1);
}

// ---------------------------------------------------------------- head MLP -> scalar (split-K)
__global__ void head_kernel(const float* __restrict__ colsum, const float* __restrict__ gf,
                            const float* __restrict__ W1, const float* __restrict__ b1,
                            const float* __restrict__ W2, const float* __restrict__ b2,
                            float* __restrict__ out) {
    __shared__ float h[448];
    __shared__ float sh[512];
    __shared__ float h1[64];
    int t = threadIdx.x;  // 512 threads
    if (t < 128) h[t] = colsum[t] * (1.0f / N_FM);
    else if (t < 256) h[t] = colsum[t] * (1.0f / N_TP);
    else if (t < 384) h[t] = colsum[t] * (1.0f / N_SM);
    else if (t < 448) h[t] = gf[t - 384];
    __syncthreads();
    {
        int col = t & 63, slice = t >> 6;  // 8 slices x 56 k
        float a = 0.0f;
        for (int k = slice * 56; k < slice * 56 + 56; k++) a += h[k] * W1[k * 64 + col];
        sh[slice * 64 + col] = a;
    }
    __syncthreads();
    if (t < 64) {
        float a = b1[t];
#pragma unroll
        for (int s = 0; s < 8; s++) a += sh[s * 64 + t];
        h1[t] = fmaxf(a, 0.0f);
    }
    __syncthreads();
    if (t < 64) {
        float p = h1[t] * W2[t];
#pragma unroll
        for (int off = 1; off < 64; off <<= 1) p += __shfl_xor(p, off);
        if (t == 0) out[0] = p + b2[0];
    }
}

extern "C" void kernel_launch(void* const* d_in, const int* in_sizes, int n_in,
                              void* d_out, int out_size, void* d_ws, size_t ws_size,
                              hipStream_t stream) {
    const float* x_fm = (const float*)d_in[0];
    const float* x_sm = (const float*)d_in[1];
    const float* period_vol = (const float*)d_in[2];
    const float* gf = (const float*)d_in[3];
    const float* pe_table = (const float*)d_in[4];
    const int* qoq_src = (const int*)d_in[5];
    const int* qoq_dst = (const int*)d_in[6];
    const int* bp_src = (const int*)d_in[7];
    const int* bp_dst = (const int*)d_in[8];
    const int* cp_src = (const int*)d_in[9];
    const int* cp_dst = (const int*)d_in[10];
    const int* cd_src = (const int*)d_in[11];
    const int* cd_dst = (const int*)d_in[12];
    const int* rb_src = (const int*)d_in[13];
    const int* rb_dst = (const int*)d_in[14];
    const float* qoq_Wl = (const float*)d_in[15];
    const float* qoq_bl = (const float*)d_in[16];
    const float* qoq_Wr = (const float*)d_in[17];
    const float* bp_Wl = (const float*)d_in[18];
    const float* bp_bl = (const float*)d_in[19];
    const float* bp_Wr = (const float*)d_in[20];
    const float* cp_Wl = (const float*)d_in[21];
    const float* cp_bl = (const float*)d_in[22];
    const float* cp_Wr = (const float*)d_in[23];
    const float* cd_Wl = (const float*)d_in[24];
    const float* cd_bl = (const float*)d_in[25];
    const float* cd_Wr = (const float*)d_in[26];
    const float* rb_Wl = (const float*)d_in[27];
    const float* rb_bl = (const float*)d_in[28];
    const float* rb_Wr = (const float*)d_in[29];
    const float* ln_fm_g = (const float*)d_in[30];
    const float* ln_fm_b = (const float*)d_in[31];
    const float* ln_tp_g = (const float*)d_in[32];
    const float* ln_tp_b = (const float*)d_in[33];
    const float* ln_sm_g = (const float*)d_in[34];
    const float* ln_sm_b = (const float*)d_in[35];
    const float* head_W1 = (const float*)d_in[36];
    const float* head_b1 = (const float*)d_in[37];
    const float* head_W2 = (const float*)d_in[38];
    const float* head_b2 = (const float*)d_in[39];

    // workspace layout (4-byte words). Zero region: combined counts + colsum.
    unsigned* wsu = (unsigned*)d_ws;
    size_t off = 0;
    int* cw = (int*)(wsu + off); off += NTOT;
    float* colsum = (float*)(wsu + off); off += 384;
    size_t zero_words = off;
    int* offs = (int*)(wsu + off); off += NTOT + 1;
    int* bsum = (int*)(wsu + off); off += NB;
    int* base = (int*)(wsu + off); off += NB;
    int* so_all = (int*)(wsu + off); off += E_TOT;
    unsigned* mean_qoq = wsu + off; off += (size_t)N_FM * 32;
    unsigned* mean_cp  = wsu + off; off += (size_t)N_FM * 16;
    unsigned* mean_rb  = wsu + off; off += (size_t)N_FM * 16;
    unsigned* mean_bp  = wsu + off; off += (size_t)N_TP * 32;
    unsigned* mean_cd  = wsu + off; off += (size_t)N_SM * 16;
    unsigned* pe_f     = wsu + off; off += (size_t)N_TP * 16;
    unsigned* x_fm_f   = wsu + off; off += (size_t)N_FM * 32;
    unsigned* x_sm_f   = wsu + off; off += (size_t)N_SM * 16;
    unsigned* wf_fm    = wsu + off; off += 96 * HID;
    unsigned* wf_tp    = wsu + off; off += 48 * HID;
    unsigned* wf_sm    = wsu + off; off += 32 * HID;

    hipMemsetAsync(d_ws, 0, zero_words * 4, stream);

    pack_all<<<(R11 + 255) / 256, 256, 0, stream>>>(
        x_fm, x_sm, pe_table, period_vol, qoq_Wl, cp_Wl, rb_Wl, qoq_Wr, cp_Wr, rb_Wr,
        bp_Wl, bp_Wr, cd_Wl, cd_Wr, x_fm_f, x_sm_f, pe_f, wf_fm, wf_tp, wf_sm);

    hist_all<<<(E_TOT + 255) / 256, 256, 0, stream>>>(qoq_dst, cp_dst, rb_dst, bp_dst, cd_dst, cw);
    scan_local<<<NB, 1024, 0, stream>>>(cw, offs, bsum);
    scan_bsums<<<1, 512, 0, stream>>>(bsum, base);
    add_base<<<(NTOT + 255) / 256, 256, 0, stream>>>(offs, cw, base);
    place_all<<<(E_TOT + 255) / 256, 256, 0, stream>>>(qoq_src, qoq_dst, cp_src, cp_dst,
                                                       rb_src, rb_dst, bp_src, bp_dst,
                                                       cd_src, cd_dst, cw, so_all);
    gather_all<<<(G5 + 255) / 256, 256, 0, stream>>>(offs, so_all, x_fm_f, pe_f,
                                                     mean_qoq, mean_cp, mean_rb, mean_bp, mean_cd);

    fm_rows2<<<2048, 128, 0, stream>>>(mean_qoq, mean_cp, mean_rb, x_fm_f, wf_fm,
                                       qoq_bl, cp_bl, rb_bl, ln_fm_g, ln_fm_b, colsum);
    rows2<32, 16><<<N_TP / TR, 128, 0, stream>>>(N_TP / TR, mean_bp, pe_f, wf_tp,
                                                 bp_bl, ln_tp_g, ln_tp_b, colsum + 128);
    rows2<16, 16><<<2048, 128, 0, stream>>>(N_SM / TR, mean_cd, x_sm_f, wf_sm,
                                            cd_bl, ln_sm_g, ln_sm_b, colsum + 256);

    head_kernel<<<1, 512, 0, stream>>>(colsum, gf, head_W1, head_b1, head_W2, head_b2,
                                       (float*)d_out);
}